// Round 1
// baseline (291.076 us; speedup 1.0000x reference)
//
#include <hip/hip_runtime.h>
#include <hip/hip_bf16.h>

#define BATCH 8
#define TDIM  2048
#define CDIM  1024
#define DDIM  128

typedef float  f32x4  __attribute__((ext_vector_type(4)));
typedef __bf16 bf16x8 __attribute__((ext_vector_type(8)));
typedef unsigned short u16;
typedef u16 u16x4 __attribute__((ext_vector_type(4)));
typedef u16 u16x8 __attribute__((ext_vector_type(8)));

static __device__ __forceinline__ u16 f2bf(float f) {
    union { float f; unsigned int u; } cv;
    cv.f = f;
    unsigned int lsb = (cv.u >> 16) & 1u;
    cv.u += 0x7fffu + lsb;          // round-to-nearest-even
    return (u16)(cv.u >> 16);
}

// ---------------------------------------------------------------------------
// Kernel 1: QKV projection.  y = x @ W^T  (x [M=16384][1024] f32, W [128][1024] f32)
// Writes Qw, Kw as bf16 [B*T][128]; V transposed as Vt bf16 [B][128][T].
// 128x128 tile, 4 waves 2x2, BK=32, mfma_f32_16x16x32_bf16.
// ---------------------------------------------------------------------------
__global__ __launch_bounds__(256) void qkv_proj(
    const float* __restrict__ x,
    const float* __restrict__ Wq,
    const float* __restrict__ Wk,
    const float* __restrict__ Wv,
    u16* __restrict__ Qw, u16* __restrict__ Kw, u16* __restrict__ Vw)
{
    constexpr int LDT = 40;                      // 32 data + 8 pad ushorts/row
    __shared__ alignas(16) u16 As[128 * LDT];
    __shared__ alignas(16) u16 Bs[128 * LDT];

    const int bid   = blockIdx.x;
    const int which = bid >> 7;                  // 0=Q 1=K 2=V
    const int mt    = bid & 127;
    const int rbase = mt * 128;
    const float* W  = (which == 0) ? Wq : (which == 1) ? Wk : Wv;

    const int tid  = threadIdx.x;
    const int wid  = tid >> 6;
    const int lane = tid & 63;
    const int g    = lane >> 4;
    const int lr   = lane & 15;
    const int wr   = (wid >> 1) * 64;            // wave row offset in tile
    const int wc   = (wid & 1) * 64;             // wave col offset in tile

    f32x4 acc[4][4] = {};

    for (int kt = 0; kt < CDIM / 32; ++kt) {
        const int k0 = kt * 32;
        // stage A (x) and B (W) tiles: 128 rows x 32 k, f32 -> bf16
        for (int it = 0; it < 4; ++it) {
            int idx = it * 256 + tid;
            int row = idx >> 3;
            int kq  = (idx & 7) * 4;
            f32x4 va = *reinterpret_cast<const f32x4*>(
                &x[(size_t)(rbase + row) * CDIM + k0 + kq]);
            u16x4 ua;
            ua[0] = f2bf(va[0]); ua[1] = f2bf(va[1]);
            ua[2] = f2bf(va[2]); ua[3] = f2bf(va[3]);
            *reinterpret_cast<u16x4*>(&As[row * LDT + kq]) = ua;
            f32x4 vb = *reinterpret_cast<const f32x4*>(
                &W[(size_t)row * CDIM + k0 + kq]);
            u16x4 ub;
            ub[0] = f2bf(vb[0]); ub[1] = f2bf(vb[1]);
            ub[2] = f2bf(vb[2]); ub[3] = f2bf(vb[3]);
            *reinterpret_cast<u16x4*>(&Bs[row * LDT + kq]) = ub;
        }
        __syncthreads();

        bf16x8 af[4], bfr[4];
        for (int mi = 0; mi < 4; ++mi)
            af[mi] = __builtin_bit_cast(bf16x8,
                *reinterpret_cast<const u16x8*>(&As[(wr + mi * 16 + lr) * LDT + g * 8]));
        for (int ni = 0; ni < 4; ++ni)
            bfr[ni] = __builtin_bit_cast(bf16x8,
                *reinterpret_cast<const u16x8*>(&Bs[(wc + ni * 16 + lr) * LDT + g * 8]));
        for (int mi = 0; mi < 4; ++mi)
            for (int ni = 0; ni < 4; ++ni)
                acc[mi][ni] = __builtin_amdgcn_mfma_f32_16x16x32_bf16(
                    af[mi], bfr[ni], acc[mi][ni], 0, 0, 0);
        __syncthreads();
    }

    // epilogue: C layout col=lane&15, row=(lane>>4)*4+reg
    for (int mi = 0; mi < 4; ++mi) {
        int m0 = rbase + wr + mi * 16 + g * 4;   // 4 consecutive rows
        for (int ni = 0; ni < 4; ++ni) {
            int col = wc + ni * 16 + lr;
            if (which < 2) {
                u16* dst = (which == 0) ? Qw : Kw;
                for (int r = 0; r < 4; ++r)
                    dst[(size_t)(m0 + r) * DDIM + col] = f2bf(acc[mi][ni][r]);
            } else {
                // V transposed: Vt[b][col][t], 4 consecutive t -> packed 8B store
                int bb = m0 >> 11;
                int t0 = m0 & 2047;
                u16x4 v;
                v[0] = f2bf(acc[mi][ni][0]); v[1] = f2bf(acc[mi][ni][1]);
                v[2] = f2bf(acc[mi][ni][2]); v[3] = f2bf(acc[mi][ni][3]);
                *reinterpret_cast<u16x4*>(
                    &Vw[((size_t)(bb * DDIM + col)) * TDIM + t0]) = v;
            }
        }
    }
}

// ---------------------------------------------------------------------------
// Kernel 2: causal flash attention.
// Grid (32 q-tiles, 8 batches), 256 threads = 4 waves x 16 q-rows. KV tile 64.
// Q in regs; K row-major, V transposed, both read from global (L2-resident).
// ---------------------------------------------------------------------------
__global__ __launch_bounds__(256) void attn(
    const u16* __restrict__ Qw, const u16* __restrict__ Kw,
    const u16* __restrict__ Vw, float* __restrict__ out)
{
    constexpr int LDP = 72;                      // 64 data + 8 pad ushorts/row
    __shared__ alignas(16) u16 Pl[4][16 * LDP];  // per-wave P tile (16x64)

    const int b    = blockIdx.y;
    const int qt   = blockIdx.x;
    const int tid  = threadIdx.x;
    const int wid  = tid >> 6;
    const int lane = tid & 63;
    const int g    = lane >> 4;
    const int lr   = lane & 15;
    const int qrow0 = qt * 64 + wid * 16;        // wave's first q row

    // Q fragments: A-layout lane holds A[l%16][(l/16)*8 + i]
    const u16* Qp = Qw + ((size_t)(b * TDIM + qrow0)) * DDIM;
    bf16x8 qf[4];
    for (int kk = 0; kk < 4; ++kk)
        qf[kk] = __builtin_bit_cast(bf16x8,
            *reinterpret_cast<const u16x8*>(&Qp[lr * DDIM + kk * 32 + g * 8]));

    f32x4 o[8] = {};
    float mrow[4] = { -1e30f, -1e30f, -1e30f, -1e30f };
    float lsum[4] = {};
    const float scale = 0.08838834764831845f;    // 1/sqrt(128)

    for (int kt = 0; kt <= qt; ++kt) {
        const int jb = kt * 64;
        const u16* Kp = Kw + ((size_t)(b * TDIM + jb)) * DDIM;

        // S = Q K^T for 4 j-subtiles of 16
        f32x4 s[4] = {};
        for (int js = 0; js < 4; ++js) {
            const u16* Kr = Kp + (js * 16 + lr) * DDIM + g * 8;
            for (int kk = 0; kk < 4; ++kk) {
                bf16x8 kf = __builtin_bit_cast(bf16x8,
                    *reinterpret_cast<const u16x8*>(&Kr[kk * 32]));
                s[js] = __builtin_amdgcn_mfma_f32_16x16x32_bf16(
                    qf[kk], kf, s[js], 0, 0, 0);
            }
        }

        const bool maskt = (kt == qt);
        // online softmax per output row r (C layout: row = g*4+r, col = lr)
        for (int r = 0; r < 4; ++r) {
            float sv[4];
            float tmax = -1e30f;
            const int q = qrow0 + g * 4 + r;
            for (int js = 0; js < 4; ++js) {
                float v = s[js][r] * scale;
                if (maskt && (jb + js * 16 + lr) > q) v = -1e30f;
                sv[js] = v;
                tmax = fmaxf(tmax, v);
            }
            for (int off = 1; off < 16; off <<= 1)
                tmax = fmaxf(tmax, __shfl_xor(tmax, off));
            float nm = fmaxf(mrow[r], tmax);
            float al = __expf(mrow[r] - nm);
            mrow[r] = nm;
            float rs = 0.f;
            for (int js = 0; js < 4; ++js) {
                float p = __expf(sv[js] - nm);
                rs += p;
                Pl[wid][(g * 4 + r) * LDP + js * 16 + lr] = f2bf(p);
            }
            for (int off = 1; off < 16; off <<= 1)
                rs += __shfl_xor(rs, off);
            lsum[r] = lsum[r] * al + rs;
            for (int dt = 0; dt < 8; ++dt)
                o[dt][r] = o[dt][r] * al;
        }

        // PV: A = P (16x32 chunks from per-wave LDS), B = Vt rows (contiguous)
        const u16* Vp = Vw + (size_t)b * DDIM * TDIM;
        for (int c = 0; c < 2; ++c) {
            bf16x8 pf = __builtin_bit_cast(bf16x8,
                *reinterpret_cast<const u16x8*>(&Pl[wid][lr * LDP + c * 32 + g * 8]));
            for (int dt = 0; dt < 8; ++dt) {
                bf16x8 vf = __builtin_bit_cast(bf16x8,
                    *reinterpret_cast<const u16x8*>(
                        &Vp[(size_t)(dt * 16 + lr) * TDIM + jb + c * 32 + g * 8]));
                o[dt] = __builtin_amdgcn_mfma_f32_16x16x32_bf16(
                    pf, vf, o[dt], 0, 0, 0);
            }
        }
    }

    // finalize: divide by l, store fp32
    float inv[4];
    for (int r = 0; r < 4; ++r) inv[r] = 1.0f / lsum[r];
    float* orow = out + ((size_t)(b * TDIM + qrow0)) * DDIM;
    for (int dt = 0; dt < 8; ++dt)
        for (int r = 0; r < 4; ++r)
            orow[(size_t)(g * 4 + r) * DDIM + dt * 16 + lr] = o[dt][r] * inv[r];
}

extern "C" void kernel_launch(void* const* d_in, const int* in_sizes, int n_in,
                              void* d_out, int out_size, void* d_ws, size_t ws_size,
                              hipStream_t stream) {
    const float* x  = (const float*)d_in[0];
    const float* Wq = (const float*)d_in[1];
    const float* Wk = (const float*)d_in[2];
    const float* Wv = (const float*)d_in[3];
    float* out = (float*)d_out;

    u16* Qw = (u16*)d_ws;                                   // [B*T][128] bf16
    u16* Kw = Qw + (size_t)BATCH * TDIM * DDIM;             // [B*T][128] bf16
    u16* Vw = Kw + (size_t)BATCH * TDIM * DDIM;             // [B][128][T] bf16

    qkv_proj<<<dim3(384), dim3(256), 0, stream>>>(x, Wq, Wk, Wv, Qw, Kw, Vw);
    attn<<<dim3(TDIM / 64, BATCH), dim3(256), 0, stream>>>(Qw, Kw, Vw, out);
}

// Round 3
// 273.485 us; speedup vs baseline: 1.0643x; 1.0643x over previous
//
#include <hip/hip_runtime.h>
#include <hip/hip_bf16.h>

#define BATCH 8
#define TDIM  2048
#define CDIM  1024
#define DDIM  128

typedef float  f32x4  __attribute__((ext_vector_type(4)));
typedef __bf16 bf16x8 __attribute__((ext_vector_type(8)));
typedef unsigned short u16;
typedef u16 u16x4 __attribute__((ext_vector_type(4)));
typedef u16 u16x8 __attribute__((ext_vector_type(8)));

static __device__ __forceinline__ u16 f2bf(float f) {
    union { float f; unsigned int u; } cv;
    cv.f = f;
    unsigned int lsb = (cv.u >> 16) & 1u;
    cv.u += 0x7fffu + lsb;          // round-to-nearest-even
    return (u16)(cv.u >> 16);
}

static __device__ __forceinline__ void gload16(const u16* g, u16* l) {
    __builtin_amdgcn_global_load_lds(
        (const __attribute__((address_space(1))) void*)g,
        (__attribute__((address_space(3))) void*)l, 16, 0, 0);
}

// ---------------------------------------------------------------------------
// Kernel 0: convert x (and Wq/Wk/Wv) fp32 -> bf16 in GEMM-tiled layout.
// Tiled layout per (panel p of 128 rows, kb of 32 k):
//   tile[cb:4][row:128][8 elems]   (elem k = kb*32 + cb*8 + e)
// so GEMM's global_load_lds source is linear and LDS fragment reads are
// conflict-free (2-way max). Writes are fully coalesced 16B/lane.
// ---------------------------------------------------------------------------
__global__ __launch_bounds__(256) void convert_tile(
    const float* __restrict__ x,
    const float* __restrict__ Wq, const float* __restrict__ Wk,
    const float* __restrict__ Wv,
    u16* __restrict__ xb, u16* __restrict__ wb)
{
    const int bid = blockIdx.x;
    const float* src;
    u16* dst;
    size_t row0;
    int kb;
    if (bid < 4096) {                       // x: 128 panels x 32 kb
        int p = bid >> 5; kb = bid & 31;
        src = x; row0 = (size_t)p * 128 * CDIM;
        dst = xb + ((size_t)p * 32 + kb) * 4096;
    } else {                                // W: 3 weights x 32 kb
        int wi = bid - 4096;
        int which = wi >> 5; kb = wi & 31;
        src = (which == 0) ? Wq : (which == 1) ? Wk : Wv;
        row0 = 0;
        dst = wb + ((size_t)which * 32 + kb) * 4096;
    }
    const int t = threadIdx.x;
    for (int i = 0; i < 2; ++i) {
        int c  = t + i * 256;               // chunk 0..511
        int cb = c >> 7, r = c & 127;
        const float* s = src + row0 + (size_t)r * CDIM + kb * 32 + cb * 8;
        f32x4 a = *reinterpret_cast<const f32x4*>(s);
        f32x4 b = *reinterpret_cast<const f32x4*>(s + 4);
        u16x8 o;
        o[0] = f2bf(a[0]); o[1] = f2bf(a[1]); o[2] = f2bf(a[2]); o[3] = f2bf(a[3]);
        o[4] = f2bf(b[0]); o[5] = f2bf(b[1]); o[6] = f2bf(b[2]); o[7] = f2bf(b[3]);
        *reinterpret_cast<u16x8*>(dst + (size_t)c * 8) = o;
    }
}

// ---------------------------------------------------------------------------
// Kernel 1: QKV GEMM, pure bf16 via global_load_lds.  128x128 tile, BK=32,
// 4 waves 2x2, m97-style 2-barrier loop.  Q gets 1/sqrt(dk) folded in.
// V written transposed: Vt[b][d][t].
// ---------------------------------------------------------------------------
__global__ __launch_bounds__(256) void qkv_gemm(
    const u16* __restrict__ xb, const u16* __restrict__ wb,
    u16* __restrict__ Qw, u16* __restrict__ Kw, u16* __restrict__ Vw)
{
    __shared__ alignas(16) u16 As[4096];    // [cb:4][row:128][8]
    __shared__ alignas(16) u16 Bs[4096];

    const int bid   = blockIdx.x;
    const int which = bid >> 7;             // 0=Q 1=K 2=V
    const int mt    = bid & 127;
    const u16* Ab = xb + (size_t)mt * 131072;          // panel base
    const u16* Bb = wb + (size_t)which * 131072;

    const int tid  = threadIdx.x;
    const int wid  = tid >> 6;
    const int lane = tid & 63;
    const int g    = lane >> 4;
    const int lr   = lane & 15;
    const int wr   = (wid >> 1) * 64;
    const int wc   = (wid & 1) * 64;

    const int stg  = wid * 512 + lane * 8;  // per-lane staging src offset (elems)
    const int stgb = wid * 512;             // wave-uniform LDS dest offset

    f32x4 acc[4][4] = {};

    for (int kb = 0; kb < 32; ++kb) {
        const u16* At = Ab + (size_t)kb * 4096;
        const u16* Bt = Bb + (size_t)kb * 4096;
        gload16(At + stg,        &As[stgb]);
        gload16(At + stg + 2048, &As[stgb + 2048]);
        gload16(Bt + stg,        &Bs[stgb]);
        gload16(Bt + stg + 2048, &Bs[stgb + 2048]);
        __syncthreads();

        bf16x8 af[4], bf[4];
        for (int mi = 0; mi < 4; ++mi)
            af[mi] = __builtin_bit_cast(bf16x8, *reinterpret_cast<const u16x8*>(
                &As[(g * 128 + wr + mi * 16 + lr) * 8]));
        for (int ni = 0; ni < 4; ++ni)
            bf[ni] = __builtin_bit_cast(bf16x8, *reinterpret_cast<const u16x8*>(
                &Bs[(g * 128 + wc + ni * 16 + lr) * 8]));
        for (int mi = 0; mi < 4; ++mi)
            for (int ni = 0; ni < 4; ++ni)
                acc[mi][ni] = __builtin_amdgcn_mfma_f32_16x16x32_bf16(
                    af[mi], bf[ni], acc[mi][ni], 0, 0, 0);
        __syncthreads();
    }

    const float sc = (which == 0) ? 0.08838834764831845f : 1.0f;  // fold 1/sqrt(dk)
    for (int mi = 0; mi < 4; ++mi) {
        int m0 = mt * 128 + wr + mi * 16 + g * 4;
        for (int ni = 0; ni < 4; ++ni) {
            int col = wc + ni * 16 + lr;
            if (which < 2) {
                u16* dst = (which == 0) ? Qw : Kw;
                for (int r = 0; r < 4; ++r)
                    dst[(size_t)(m0 + r) * DDIM + col] = f2bf(acc[mi][ni][r] * sc);
            } else {
                int bb = m0 >> 11, t0 = m0 & 2047;
                u16x4 v;
                v[0] = f2bf(acc[mi][ni][0]); v[1] = f2bf(acc[mi][ni][1]);
                v[2] = f2bf(acc[mi][ni][2]); v[3] = f2bf(acc[mi][ni][3]);
                *reinterpret_cast<u16x4*>(
                    &Vw[((size_t)(bb * DDIM + col)) * TDIM + t0]) = v;
            }
        }
    }
}

// ---------------------------------------------------------------------------
// Kernel 2: causal flash attention with split-KV.
// Grid (80, 8): 80 = sum over qt of ceil((qt+1)/8) work blocks per batch.
// Each block: 4 waves x 16 q-rows (64-row q-tile), <=8 KV tiles of 64.
// Single-split q-tiles (qt<8) write out directly; others write f32 partials.
// ---------------------------------------------------------------------------
__global__ __launch_bounds__(256) void attn(
    const u16* __restrict__ Qw, const u16* __restrict__ Kw,
    const u16* __restrict__ Vw, float* __restrict__ out,
    float* __restrict__ po, float* __restrict__ pm, float* __restrict__ pl)
{
    constexpr int LDP = 72;
    __shared__ alignas(16) u16 Pl[4][16 * LDP];

    const int s = blockIdx.x;
    const int b = blockIdx.y;
    int gg, rr_;
    if (s < 8)       { gg = 0; rr_ = s; }
    else if (s < 24) { gg = 1; rr_ = s - 8; }
    else if (s < 48) { gg = 2; rr_ = s - 24; }
    else             { gg = 3; rr_ = s - 48; }
    const int qt     = (gg << 3) + rr_ / (gg + 1);
    const int split  = rr_ % (gg + 1);
    const int nsplit = gg + 1;
    const int kt0 = split * 8;
    const int kt1 = min(kt0 + 8, qt + 1);

    const int tid  = threadIdx.x;
    const int wid  = tid >> 6;
    const int lane = tid & 63;
    const int g    = lane >> 4;
    const int lr   = lane & 15;
    const int qrow0 = qt * 64 + wid * 16;

    const u16* Qp = Qw + ((size_t)(b * TDIM + qrow0)) * DDIM;
    bf16x8 qf[4];
    for (int kk = 0; kk < 4; ++kk)
        qf[kk] = __builtin_bit_cast(bf16x8, *reinterpret_cast<const u16x8*>(
            &Qp[lr * DDIM + kk * 32 + g * 8]));

    f32x4 o[8] = {};
    float mrow[4] = { -1e30f, -1e30f, -1e30f, -1e30f };
    float lsum[4] = {};

    const u16* Vp = Vw + (size_t)b * DDIM * TDIM;

    for (int kt = kt0; kt < kt1; ++kt) {
        const int jb = kt * 64;
        const u16* Kp = Kw + ((size_t)(b * TDIM + jb)) * DDIM;

        f32x4 sf[4] = {};
        for (int js = 0; js < 4; ++js) {
            const u16* Kr = Kp + (js * 16 + lr) * DDIM + g * 8;
            for (int kk = 0; kk < 4; ++kk) {
                bf16x8 kf = __builtin_bit_cast(bf16x8,
                    *reinterpret_cast<const u16x8*>(&Kr[kk * 32]));
                sf[js] = __builtin_amdgcn_mfma_f32_16x16x32_bf16(
                    qf[kk], kf, sf[js], 0, 0, 0);
            }
        }

        const bool maskt = (kt == qt);
        for (int r = 0; r < 4; ++r) {
            float sv[4];
            float tmax = -1e30f;
            const int q = qrow0 + g * 4 + r;
            for (int js = 0; js < 4; ++js) {
                float v = sf[js][r];
                if (maskt && (jb + js * 16 + lr) > q) v = -1e30f;
                sv[js] = v;
                tmax = fmaxf(tmax, v);
            }
            for (int off = 1; off < 16; off <<= 1)
                tmax = fmaxf(tmax, __shfl_xor(tmax, off));
            float nm = fmaxf(mrow[r], tmax);
            float al = __expf(mrow[r] - nm);
            mrow[r] = nm;
            float rs = 0.f;
            for (int js = 0; js < 4; ++js) {
                float p = __expf(sv[js] - nm);
                rs += p;
                Pl[wid][(g * 4 + r) * LDP + js * 16 + lr] = f2bf(p);
            }
            for (int off = 1; off < 16; off <<= 1)
                rs += __shfl_xor(rs, off);
            lsum[r] = lsum[r] * al + rs;
            for (int dt = 0; dt < 8; ++dt)
                o[dt][r] = o[dt][r] * al;
        }

        for (int c = 0; c < 2; ++c) {
            bf16x8 pf = __builtin_bit_cast(bf16x8, *reinterpret_cast<const u16x8*>(
                &Pl[wid][lr * LDP + c * 32 + g * 8]));
            for (int dt = 0; dt < 8; ++dt) {
                bf16x8 vf = __builtin_bit_cast(bf16x8, *reinterpret_cast<const u16x8*>(
                    &Vp[(size_t)(dt * 16 + lr) * TDIM + jb + c * 32 + g * 8]));
                o[dt] = __builtin_amdgcn_mfma_f32_16x16x32_bf16(
                    pf, vf, o[dt], 0, 0, 0);
            }
        }
    }

    if (nsplit == 1) {
        float inv[4];
        for (int r = 0; r < 4; ++r) inv[r] = 1.0f / lsum[r];
        float* orow = out + ((size_t)(b * TDIM + qrow0)) * DDIM;
        for (int dt = 0; dt < 8; ++dt)
            for (int r = 0; r < 4; ++r)
                orow[(size_t)(g * 4 + r) * DDIM + dt * 16 + lr] = o[dt][r] * inv[r];
    } else {
        const int slot = (b * 32 + qt) * 4 + split;
        float* pob = po + (size_t)slot * 8192 + (size_t)(wid * 16) * 128;
        for (int dt = 0; dt < 8; ++dt)
            for (int r = 0; r < 4; ++r)
                pob[(size_t)(g * 4 + r) * 128 + dt * 16 + lr] = o[dt][r];
        if (lr == 0) {
            for (int r = 0; r < 4; ++r) {
                int row = wid * 16 + g * 4 + r;
                pm[slot * 64 + row] = mrow[r];
                pl[slot * 64 + row] = lsum[r];
            }
        }
    }
}

// ---------------------------------------------------------------------------
// Kernel 3: combine split-KV partials for qt >= 8.
// ---------------------------------------------------------------------------
__global__ __launch_bounds__(256) void combine(
    const float* __restrict__ po, const float* __restrict__ pm,
    const float* __restrict__ pl, float* __restrict__ out)
{
    const int qt = 8 + blockIdx.x;          // 8..31
    const int b  = blockIdx.y;
    const int nsplit = (qt >> 3) + 1;
    const int tid = threadIdx.x;
    const int c4 = (tid & 31) * 4;
    const int r0 = tid >> 5;
    const int slot0 = (b * 32 + qt) * 4;

    for (int rr = r0; rr < 64; rr += 8) {
        float M = -1e30f;
        float mv[4], wv[4];
        #pragma unroll 4
        for (int i = 0; i < 4; ++i)
            if (i < nsplit) { mv[i] = pm[(slot0 + i) * 64 + rr]; M = fmaxf(M, mv[i]); }
        float L = 0.f;
        #pragma unroll 4
        for (int i = 0; i < 4; ++i)
            if (i < nsplit) { wv[i] = __expf(mv[i] - M); L += pl[(slot0 + i) * 64 + rr] * wv[i]; }
        f32x4 acc = {};
        #pragma unroll 4
        for (int i = 0; i < 4; ++i)
            if (i < nsplit) {
                f32x4 v = *reinterpret_cast<const f32x4*>(
                    &po[(size_t)(slot0 + i) * 8192 + (size_t)rr * 128 + c4]);
                acc[0] += v[0] * wv[i]; acc[1] += v[1] * wv[i];
                acc[2] += v[2] * wv[i]; acc[3] += v[3] * wv[i];
            }
        float invL = 1.0f / L;
        acc[0] *= invL; acc[1] *= invL; acc[2] *= invL; acc[3] *= invL;
        *reinterpret_cast<f32x4*>(
            &out[((size_t)(b * TDIM) + qt * 64 + rr) * DDIM + c4]) = acc;
    }
}

extern "C" void kernel_launch(void* const* d_in, const int* in_sizes, int n_in,
                              void* d_out, int out_size, void* d_ws, size_t ws_size,
                              hipStream_t stream) {
    const float* x  = (const float*)d_in[0];
    const float* Wq = (const float*)d_in[1];
    const float* Wk = (const float*)d_in[2];
    const float* Wv = (const float*)d_in[3];
    float* out = (float*)d_out;

    char* base = (char*)d_ws;
    u16*   xb = (u16*)base;                          // 32 MB (tiled bf16 x)
    float* po = (float*)base;                        // reused after qkv: 32 MB partials
    u16*   wb = (u16*)(base + 33554432);             // 768 KB (tiled bf16 W)
    u16*   Qw = (u16*)(base + 34340864);             // 4 MB
    u16*   Kw = (u16*)(base + 38535168);             // 4 MB
    u16*   Vw = (u16*)(base + 42729472);             // 4 MB (transposed V)
    float* pm = (float*)(base + 46923776);           // 256 KB
    float* pl = (float*)(base + 47185920);           // 256 KB

    convert_tile<<<dim3(4192), dim3(256), 0, stream>>>(x, Wq, Wk, Wv, xb, wb);
    qkv_gemm<<<dim3(384), dim3(256), 0, stream>>>(xb, wb, Qw, Kw, Vw);
    attn<<<dim3(80, BATCH), dim3(256), 0, stream>>>(Qw, Kw, Vw, out, po, pm, pl);
    combine<<<dim3(24, BATCH), dim3(256), 0, stream>>>(po, pm, pl, out);
}

// Round 4
// 255.433 us; speedup vs baseline: 1.1395x; 1.0707x over previous
//
#include <hip/hip_runtime.h>
#include <hip/hip_bf16.h>

#define BATCH 8
#define TDIM  2048
#define CDIM  1024
#define DDIM  128

typedef float  f32x4  __attribute__((ext_vector_type(4)));
typedef __bf16 bf16x8 __attribute__((ext_vector_type(8)));
typedef unsigned short u16;
typedef unsigned int   u32;
typedef u16 u16x4 __attribute__((ext_vector_type(4)));
typedef u16 u16x8 __attribute__((ext_vector_type(8)));
typedef u32 u32x4 __attribute__((ext_vector_type(4)));

static __device__ __forceinline__ u16 f2bf(float f) {
    union { float f; unsigned int u; } cv;
    cv.f = f;
    unsigned int lsb = (cv.u >> 16) & 1u;
    cv.u += 0x7fffu + lsb;          // round-to-nearest-even
    return (u16)(cv.u >> 16);
}

static __device__ __forceinline__ u32 packbf(float a, float b) {
    return (u32)f2bf(a) | ((u32)f2bf(b) << 16);
}

static __device__ __forceinline__ void gload16(const u16* g, u16* l) {
    __builtin_amdgcn_global_load_lds(
        (const __attribute__((address_space(1))) void*)g,
        (__attribute__((address_space(3))) void*)l, 16, 0, 0);
}

// ---------------------------------------------------------------------------
// Kernel 0: convert x / W fp32 -> bf16 in GEMM-tiled layout.
// Tile (panel p of 128 rows, kb of 32 k): [cb:4][row:128][8]  (k = kb*32+cb*8+e)
// Reads: 8 lanes x 16B per row = 128B contiguous/row.  Writes: per wave,
// 4 chunks of 128B contiguous.  Both cache-line coalesced.
// ---------------------------------------------------------------------------
__global__ __launch_bounds__(256) void convert_tile(
    const float* __restrict__ x,
    const float* __restrict__ Wq, const float* __restrict__ Wk,
    const float* __restrict__ Wv,
    u16* __restrict__ xb, u16* __restrict__ wb)
{
    const int bid = blockIdx.x;
    const float* src;
    u16* dst;
    int rowbase, kb;
    if (bid < 4096) {                       // x: 128 panels x 32 kb
        int p = bid >> 5; kb = bid & 31;
        src = x; rowbase = p * 128;
        dst = xb + ((size_t)(p * 32 + kb)) * 4096;
    } else {                                // W: 3 weights x 32 kb
        int wi = bid - 4096;
        int which = wi >> 5; kb = wi & 31;
        src = (which == 0) ? Wq : (which == 1) ? Wk : Wv;
        rowbase = 0;
        dst = wb + ((size_t)(which * 32 + kb)) * 4096;
    }
    const int t    = threadIdx.x;
    const int lr8  = t & 7;                 // k-subchunk 0..7 (4 f32 each)
    const int cb   = lr8 >> 1;
    const int half = lr8 & 1;
    for (int i = 0; i < 4; ++i) {
        int rowp = i * 32 + (t >> 3);
        f32x4 v = *reinterpret_cast<const f32x4*>(
            &src[(size_t)(rowbase + rowp) * CDIM + kb * 32 + lr8 * 4]);
        u16x4 o;
        o[0] = f2bf(v[0]); o[1] = f2bf(v[1]); o[2] = f2bf(v[2]); o[3] = f2bf(v[3]);
        *reinterpret_cast<u16x4*>(&dst[cb * 1024 + rowp * 8 + half * 4]) = o;
    }
}

// ---------------------------------------------------------------------------
// Kernel 1: QKV GEMM, 64x128 tile, BK=32, 4 waves 1x4, global_load_lds.
// Grid 768 (= 3 weights x 256 row-tiles) -> 3 blocks/CU for latency overlap.
// Q gets 1/sqrt(dk) folded in.  V written transposed: Vt[b][d][t].
// ---------------------------------------------------------------------------
__global__ __launch_bounds__(256) void qkv_gemm(
    const u16* __restrict__ xb, const u16* __restrict__ wb,
    u16* __restrict__ Qw, u16* __restrict__ Kw, u16* __restrict__ Vw)
{
    __shared__ alignas(16) u16 As[2048];    // [cb:4][row:64][8]
    __shared__ alignas(16) u16 Bs[4096];    // [cb:4][row:128][8]

    const int bid   = blockIdx.x;
    const int which = bid >> 8;             // 0=Q 1=K 2=V
    const int mt    = bid & 255;            // 64-row tile index
    const u16* Ab = xb + (size_t)(mt >> 1) * 131072 + (mt & 1) * 512;
    const u16* Bb = wb + (size_t)which * 131072;

    const int tid  = threadIdx.x;
    const int wid  = tid >> 6;
    const int lane = tid & 63;
    const int g    = lane >> 4;
    const int lr   = lane & 15;
    const int wc   = wid * 32;

    f32x4 acc[4][2] = {};

    for (int kb = 0; kb < 32; ++kb) {
        const u16* At = Ab + (size_t)kb * 4096;
        const u16* Bt = Bb + (size_t)kb * 4096;
        gload16(At + wid * 1024 + lane * 8, &As[wid * 512]);
        gload16(Bt + (tid)       * 8, &Bs[wid * 512]);
        gload16(Bt + (256 + tid) * 8, &Bs[2048 + wid * 512]);
        __syncthreads();

        bf16x8 af[4], bf[2];
        for (int mi = 0; mi < 4; ++mi)
            af[mi] = __builtin_bit_cast(bf16x8, *reinterpret_cast<const u16x8*>(
                &As[g * 512 + (mi * 16 + lr) * 8]));
        for (int ni = 0; ni < 2; ++ni)
            bf[ni] = __builtin_bit_cast(bf16x8, *reinterpret_cast<const u16x8*>(
                &Bs[g * 1024 + (wc + ni * 16 + lr) * 8]));
        for (int mi = 0; mi < 4; ++mi)
            for (int ni = 0; ni < 2; ++ni)
                acc[mi][ni] = __builtin_amdgcn_mfma_f32_16x16x32_bf16(
                    af[mi], bf[ni], acc[mi][ni], 0, 0, 0);
        __syncthreads();
    }

    const float sc = (which == 0) ? 0.08838834764831845f : 1.0f;
    for (int mi = 0; mi < 4; ++mi) {
        int m0 = mt * 64 + mi * 16 + g * 4;
        for (int ni = 0; ni < 2; ++ni) {
            int col = wc + ni * 16 + lr;
            if (which < 2) {
                u16* dst = (which == 0) ? Qw : Kw;
                for (int r = 0; r < 4; ++r)
                    dst[(size_t)(m0 + r) * DDIM + col] = f2bf(acc[mi][ni][r] * sc);
            } else {
                int bb = m0 >> 11, t0 = m0 & 2047;
                u16x4 v;
                v[0] = f2bf(acc[mi][ni][0]); v[1] = f2bf(acc[mi][ni][1]);
                v[2] = f2bf(acc[mi][ni][2]); v[3] = f2bf(acc[mi][ni][3]);
                *reinterpret_cast<u16x4*>(
                    &Vw[((size_t)(bb * DDIM + col)) * TDIM + t0]) = v;
            }
        }
    }
}

// ---------------------------------------------------------------------------
// Kernel 2: causal flash attention, split-KV, SWAPPED QK^T.
// s = mfma(K, Q) -> S^T: lane(g,lr) holds kv = js*16+g*4+r for q-row lr.
// Softmax: in-lane over 16 + 2 shfl_xor (16,32); m/l scalar per lane.
// P -> per-wave LDS (8x ds_write_b32, 2-way) -> A-frag reads for PV.
// ---------------------------------------------------------------------------
__global__ __launch_bounds__(256) void attn(
    const u16* __restrict__ Qw, const u16* __restrict__ Kw,
    const u16* __restrict__ Vw, float* __restrict__ out,
    float* __restrict__ po, float* __restrict__ pm, float* __restrict__ pl)
{
    constexpr int LDPW = 36;                     // 32 data dwords + 4 pad
    __shared__ u32 Plw[4][16 * LDPW];            // per-wave P tile [q:16][kv/2:32]

    const int s = blockIdx.x;
    const int b = blockIdx.y;
    int gg, rr_;
    if (s < 8)       { gg = 0; rr_ = s; }
    else if (s < 24) { gg = 1; rr_ = s - 8; }
    else if (s < 48) { gg = 2; rr_ = s - 24; }
    else             { gg = 3; rr_ = s - 48; }
    const int qt     = (gg << 3) + rr_ / (gg + 1);
    const int split  = rr_ % (gg + 1);
    const int nsplit = gg + 1;
    const int kt0 = split * 8;
    const int kt1 = min(kt0 + 8, qt + 1);

    const int tid  = threadIdx.x;
    const int wid  = tid >> 6;
    const int lane = tid & 63;
    const int g    = lane >> 4;
    const int lr   = lane & 15;
    const int qrow0 = qt * 64 + wid * 16;

    const u16* Qp = Qw + ((size_t)(b * TDIM + qrow0)) * DDIM;
    bf16x8 qf[4];
    for (int kk = 0; kk < 4; ++kk)
        qf[kk] = __builtin_bit_cast(bf16x8, *reinterpret_cast<const u16x8*>(
            &Qp[lr * DDIM + kk * 32 + g * 8]));

    f32x4 o[8] = {};
    float mrow = -1e30f;                         // per-lane: q = qrow0 + lr
    float lsum = 0.f;
    const int q = qrow0 + lr;

    const u16* Vp = Vw + (size_t)b * DDIM * TDIM;
    u32* Pw = &Plw[wid][0];

    for (int kt = kt0; kt < kt1; ++kt) {
        const int jb = kt * 64;
        const u16* Kp = Kw + ((size_t)(b * TDIM + jb)) * DDIM;

        // S^T = K Q^T: row = kv-subrow, col = q
        f32x4 sf[4] = {};
        for (int js = 0; js < 4; ++js) {
            const u16* Kr = Kp + (js * 16 + lr) * DDIM + g * 8;
            for (int kk = 0; kk < 4; ++kk) {
                bf16x8 kf = __builtin_bit_cast(bf16x8,
                    *reinterpret_cast<const u16x8*>(&Kr[kk * 32]));
                sf[js] = __builtin_amdgcn_mfma_f32_16x16x32_bf16(
                    kf, qf[kk], sf[js], 0, 0, 0);
            }
        }

        // ---- in-register online softmax (per-lane scalar m/l) ----
        float pv[4][4];
        float tmax = -1e30f;
        const bool maskt = (kt == qt);
        const int kvb = jb + g * 4;
        for (int js = 0; js < 4; ++js)
            for (int r = 0; r < 4; ++r) {
                float v = sf[js][r];
                if (maskt && (kvb + js * 16 + r) > q) v = -1e30f;
                pv[js][r] = v;
                tmax = fmaxf(tmax, v);
            }
        tmax = fmaxf(tmax, __shfl_xor(tmax, 16));
        tmax = fmaxf(tmax, __shfl_xor(tmax, 32));
        float nm = fmaxf(mrow, tmax);
        float al = __expf(mrow - nm);
        mrow = nm;
        float rs = 0.f;
        for (int js = 0; js < 4; ++js)
            for (int r = 0; r < 4; ++r) {
                float p = __expf(pv[js][r] - nm);
                pv[js][r] = p;
                rs += p;
            }
        rs += __shfl_xor(rs, 16);
        rs += __shfl_xor(rs, 32);
        lsum = lsum * al + rs;

        // P -> LDS: dword (q=lr) row, kv/2 col.  2-way bank (free).
        for (int js = 0; js < 4; ++js) {
            Pw[lr * LDPW + js * 8 + g * 2 + 0] = packbf(pv[js][0], pv[js][1]);
            Pw[lr * LDPW + js * 8 + g * 2 + 1] = packbf(pv[js][2], pv[js][3]);
        }

        // transport al to O domain (row = g*4+r) and rescale
        float alo[4];
        for (int r = 0; r < 4; ++r)
            alo[r] = __shfl(al, g * 20 + r);
        for (int dt = 0; dt < 8; ++dt)
            for (int r = 0; r < 4; ++r)
                o[dt][r] *= alo[r];

        // PV: A = P (from per-wave LDS), B = Vt rows (contiguous)
        for (int c = 0; c < 2; ++c) {
            u32x4 prd = *reinterpret_cast<const u32x4*>(
                &Pw[lr * LDPW + c * 16 + g * 4]);
            bf16x8 pf = __builtin_bit_cast(bf16x8, prd);
            for (int dt = 0; dt < 8; ++dt) {
                bf16x8 vf = __builtin_bit_cast(bf16x8, *reinterpret_cast<const u16x8*>(
                    &Vp[(size_t)(dt * 16 + lr) * TDIM + jb + c * 32 + g * 8]));
                o[dt] = __builtin_amdgcn_mfma_f32_16x16x32_bf16(
                    pf, vf, o[dt], 0, 0, 0);
            }
        }
    }

    if (nsplit == 1) {
        float linv = 1.0f / lsum;
        float linvo[4];
        for (int r = 0; r < 4; ++r)
            linvo[r] = __shfl(linv, g * 20 + r);
        float* orow = out + ((size_t)(b * TDIM + qrow0)) * DDIM;
        for (int dt = 0; dt < 8; ++dt)
            for (int r = 0; r < 4; ++r)
                orow[(size_t)(g * 4 + r) * DDIM + dt * 16 + lr] = o[dt][r] * linvo[r];
    } else {
        const int slot = (b * 32 + qt) * 4 + split;
        float* pob = po + (size_t)slot * 8192 + (size_t)(wid * 16) * 128;
        for (int dt = 0; dt < 8; ++dt)
            for (int r = 0; r < 4; ++r)
                pob[(size_t)(g * 4 + r) * 128 + dt * 16 + lr] = o[dt][r];
        if (g == 0) {
            pm[slot * 64 + wid * 16 + lr] = mrow;
            pl[slot * 64 + wid * 16 + lr] = lsum;
        }
    }
}

// ---------------------------------------------------------------------------
// Kernel 3: combine split-KV partials for qt >= 8.
// ---------------------------------------------------------------------------
__global__ __launch_bounds__(256) void combine(
    const float* __restrict__ po, const float* __restrict__ pm,
    const float* __restrict__ pl, float* __restrict__ out)
{
    const int qt = 8 + blockIdx.x;          // 8..31
    const int b  = blockIdx.y;
    const int nsplit = (qt >> 3) + 1;
    const int tid = threadIdx.x;
    const int c4 = (tid & 31) * 4;
    const int r0 = tid >> 5;
    const int slot0 = (b * 32 + qt) * 4;

    for (int rr = r0; rr < 64; rr += 8) {
        float M = -1e30f;
        float mv[4], wv[4];
        #pragma unroll 4
        for (int i = 0; i < 4; ++i)
            if (i < nsplit) { mv[i] = pm[(slot0 + i) * 64 + rr]; M = fmaxf(M, mv[i]); }
        float L = 0.f;
        #pragma unroll 4
        for (int i = 0; i < 4; ++i)
            if (i < nsplit) { wv[i] = __expf(mv[i] - M); L += pl[(slot0 + i) * 64 + rr] * wv[i]; }
        f32x4 acc = {};
        #pragma unroll 4
        for (int i = 0; i < 4; ++i)
            if (i < nsplit) {
                f32x4 v = *reinterpret_cast<const f32x4*>(
                    &po[(size_t)(slot0 + i) * 8192 + (size_t)rr * 128 + c4]);
                acc[0] += v[0] * wv[i]; acc[1] += v[1] * wv[i];
                acc[2] += v[2] * wv[i]; acc[3] += v[3] * wv[i];
            }
        float invL = 1.0f / L;
        acc[0] *= invL; acc[1] *= invL; acc[2] *= invL; acc[3] *= invL;
        *reinterpret_cast<f32x4*>(
            &out[((size_t)(b * TDIM) + qt * 64 + rr) * DDIM + c4]) = acc;
    }
}

extern "C" void kernel_launch(void* const* d_in, const int* in_sizes, int n_in,
                              void* d_out, int out_size, void* d_ws, size_t ws_size,
                              hipStream_t stream) {
    const float* x  = (const float*)d_in[0];
    const float* Wq = (const float*)d_in[1];
    const float* Wk = (const float*)d_in[2];
    const float* Wv = (const float*)d_in[3];
    float* out = (float*)d_out;

    char* base = (char*)d_ws;
    u16*   xb = (u16*)base;                          // 32 MB (tiled bf16 x)
    float* po = (float*)base;                        // reused after qkv: 32 MB partials
    u16*   wb = (u16*)(base + 33554432);             // 768 KB (tiled bf16 W)
    u16*   Qw = (u16*)(base + 34340864);             // 4 MB
    u16*   Kw = (u16*)(base + 38535168);             // 4 MB
    u16*   Vw = (u16*)(base + 42729472);             // 4 MB (transposed V)
    float* pm = (float*)(base + 46923776);           // 256 KB
    float* pl = (float*)(base + 47185920);           // 256 KB

    convert_tile<<<dim3(4192), dim3(256), 0, stream>>>(x, Wq, Wk, Wv, xb, wb);
    qkv_gemm<<<dim3(768), dim3(256), 0, stream>>>(xb, wb, Qw, Kw, Vw);
    attn<<<dim3(80, BATCH), dim3(256), 0, stream>>>(Qw, Kw, Vw, out, po, pm, pl);
    combine<<<dim3(24, BATCH), dim3(256), 0, stream>>>(po, pm, pl, out);
}

// Round 5
// 159.859 us; speedup vs baseline: 1.8208x; 1.5979x over previous
//
#include <hip/hip_runtime.h>
#include <hip/hip_bf16.h>

#define BATCH 8
#define TDIM  2048
#define CDIM  1024
#define DDIM  128

typedef float  f32x4  __attribute__((ext_vector_type(4)));
typedef __bf16 bf16x8 __attribute__((ext_vector_type(8)));
typedef unsigned short u16;
typedef unsigned int   u32;
typedef u16 u16x4 __attribute__((ext_vector_type(4)));
typedef u16 u16x8 __attribute__((ext_vector_type(8)));
typedef u32 u32x4 __attribute__((ext_vector_type(4)));

static __device__ __forceinline__ u16 f2bf(float f) {
    union { float f; unsigned int u; } cv;
    cv.f = f;
    unsigned int lsb = (cv.u >> 16) & 1u;
    cv.u += 0x7fffu + lsb;          // round-to-nearest-even
    return (u16)(cv.u >> 16);
}

static __device__ __forceinline__ float bf2f(u16 v) {
    union { u32 u; float f; } cv;
    cv.u = (u32)v << 16;
    return cv.f;
}

static __device__ __forceinline__ u32 packbf(float a, float b) {
    return (u32)f2bf(a) | ((u32)f2bf(b) << 16);
}

static __device__ __forceinline__ void gload16(const u16* g, u16* l) {
    __builtin_amdgcn_global_load_lds(
        (const __attribute__((address_space(1))) void*)g,
        (__attribute__((address_space(3))) void*)l, 16, 0, 0);
}

// ---------------------------------------------------------------------------
// Kernel 0: W fp32 -> tiled bf16.  wb[which][kb:16][kk2:2][cb:4][row:128][8]
// (k = kb*64 + kk2*32 + cb*8 + e).  48 blocks, tiny.
// ---------------------------------------------------------------------------
__global__ __launch_bounds__(256) void convert_w(
    const float* __restrict__ Wq, const float* __restrict__ Wk,
    const float* __restrict__ Wv, u16* __restrict__ wb)
{
    const int which = blockIdx.x >> 4;
    const int kb    = blockIdx.x & 15;
    const float* W = (which == 0) ? Wq : (which == 1) ? Wk : Wv;
    u16* dst = wb + ((size_t)(which * 16 + kb)) * 8192;
    const int t = threadIdx.x;
    for (int i = 0; i < 4; ++i) {
        int j   = i * 256 + t;              // 0..1023 = kk2*512 + cb*128 + row
        int row = j & 127;
        int cb  = (j >> 7) & 3;
        int kk2 = j >> 9;
        const float* s = &W[(size_t)row * CDIM + kb * 64 + kk2 * 32 + cb * 8];
        f32x4 a = *reinterpret_cast<const f32x4*>(s);
        f32x4 b = *reinterpret_cast<const f32x4*>(s + 4);
        u16x8 o;
        o[0] = f2bf(a[0]); o[1] = f2bf(a[1]); o[2] = f2bf(a[2]); o[3] = f2bf(a[3]);
        o[4] = f2bf(b[0]); o[5] = f2bf(b[1]); o[6] = f2bf(b[2]); o[7] = f2bf(b[3]);
        *reinterpret_cast<u16x8*>(dst + (size_t)j * 8) = o;
    }
}

// ---------------------------------------------------------------------------
// Kernel 1: fused QKV GEMM.  x fp32 read directly (convert in-reg while
// staging A), W from pre-tiled wb via global_load_lds.  64x128 tile, BK=64,
// 4 waves (each: 64 rows x 32 cols).  Grid 768 = 3 x 256 row-tiles.
// Epilogue bounces through LDS to write:
//   Q row-major [t][128] (scaled by 1/sqrt(dk))
//   K tiles Ktl[b][kt][kk:4][cb:4][row:64][8]   (d = kk*32+cb*8+e)
//   V tiles Vtl[b][kt][c:2][gk:4][d:128][8]     (t_loc = c*32+gk*8+e)
// ---------------------------------------------------------------------------
__global__ __launch_bounds__(256) void qkv_gemm(
    const float* __restrict__ x, const u16* __restrict__ wb,
    u16* __restrict__ Qw, u16* __restrict__ Ktl, u16* __restrict__ Vtl)
{
    __shared__ alignas(16) u16 As[4096];    // 8KB  [kk2:2][cb:4][row:64][8]
    __shared__ alignas(16) u16 Bs[8192];    // 16KB [kk2:2][cb:4][row:128][8]; reused as bounce

    const int bid   = blockIdx.x;
    const int which = bid >> 8;             // 0=Q 1=K 2=V
    const int mt    = bid & 255;            // 64-row tile
    const int rbase = mt * 64;
    const u16* Bb = wb + (size_t)which * 131072;

    const int tid  = threadIdx.x;
    const int wid  = tid >> 6;
    const int lane = tid & 63;
    const int g    = lane >> 4;
    const int lr   = lane & 15;
    const int wc   = wid * 32;

    const int arow = tid >> 2;              // 0..63
    const int aseg = tid & 3;               // 16 k-values each
    const int abase = (aseg >> 1) * 2048 + (aseg & 1) * 1024 + arow * 8;

    f32x4 acc[4][2] = {};

    for (int kb = 0; kb < 16; ++kb) {
        // --- stage A: rows 64 x k 64 fp32 -> bf16 tiled ---
        const float* ax = &x[(size_t)(rbase + arow) * CDIM + kb * 64 + aseg * 16];
        f32x4 v0 = *reinterpret_cast<const f32x4*>(ax);
        f32x4 v1 = *reinterpret_cast<const f32x4*>(ax + 4);
        f32x4 v2 = *reinterpret_cast<const f32x4*>(ax + 8);
        f32x4 v3 = *reinterpret_cast<const f32x4*>(ax + 12);
        u16x8 p0, p1;
        p0[0]=f2bf(v0[0]); p0[1]=f2bf(v0[1]); p0[2]=f2bf(v0[2]); p0[3]=f2bf(v0[3]);
        p0[4]=f2bf(v1[0]); p0[5]=f2bf(v1[1]); p0[6]=f2bf(v1[2]); p0[7]=f2bf(v1[3]);
        p1[0]=f2bf(v2[0]); p1[1]=f2bf(v2[1]); p1[2]=f2bf(v2[2]); p1[3]=f2bf(v2[3]);
        p1[4]=f2bf(v3[0]); p1[5]=f2bf(v3[1]); p1[6]=f2bf(v3[2]); p1[7]=f2bf(v3[3]);
        *reinterpret_cast<u16x8*>(&As[abase])       = p0;
        *reinterpret_cast<u16x8*>(&As[abase + 512]) = p1;
        // --- stage B: pre-tiled, linear ---
        const u16* Bt = Bb + (size_t)kb * 8192;
        for (int i = 0; i < 4; ++i)
            gload16(Bt + (size_t)(i * 256 + tid) * 8, &Bs[(i * 256 + wid * 64) * 8]);
        __syncthreads();

        bf16x8 af[2][4], bf[2][2];
        for (int kk2 = 0; kk2 < 2; ++kk2) {
            for (int mi = 0; mi < 4; ++mi)
                af[kk2][mi] = __builtin_bit_cast(bf16x8, *reinterpret_cast<const u16x8*>(
                    &As[kk2 * 2048 + g * 512 + (mi * 16 + lr) * 8]));
            for (int ni = 0; ni < 2; ++ni)
                bf[kk2][ni] = __builtin_bit_cast(bf16x8, *reinterpret_cast<const u16x8*>(
                    &Bs[kk2 * 4096 + g * 1024 + (wc + ni * 16 + lr) * 8]));
        }
        for (int kk2 = 0; kk2 < 2; ++kk2)
            for (int mi = 0; mi < 4; ++mi)
                for (int ni = 0; ni < 2; ++ni)
                    acc[mi][ni] = __builtin_amdgcn_mfma_f32_16x16x32_bf16(
                        af[kk2][mi], bf[kk2][ni], acc[mi][ni], 0, 0, 0);
        __syncthreads();
    }

    // --- epilogue: bounce through Bs (16KB), then linear 16B writes ---
    const int b  = mt >> 5;
    const int kt = mt & 31;
    if (which == 0) {
        const float sc = 0.08838834764831845f;   // 1/sqrt(128)
        for (int mi = 0; mi < 4; ++mi)
            for (int ni = 0; ni < 2; ++ni) {
                int row = mi * 16 + g * 4;
                int col = wc + ni * 16 + lr;
                for (int r = 0; r < 4; ++r)
                    Bs[(row + r) * 128 + col] = f2bf(acc[mi][ni][r] * sc);
            }
        __syncthreads();
        u16* dst = Qw + (size_t)rbase * DDIM;
        for (int i = 0; i < 4; ++i)
            *reinterpret_cast<u16x8*>(&dst[(size_t)(i * 256 + tid) * 8]) =
                *reinterpret_cast<const u16x8*>(&Bs[(i * 256 + tid) * 8]);
    } else if (which == 1) {
        for (int mi = 0; mi < 4; ++mi)
            for (int ni = 0; ni < 2; ++ni) {
                int row = mi * 16 + g * 4;
                int col = wc + ni * 16 + lr;               // d
                int ebase = (col >> 5) * 2048 + ((col >> 3) & 3) * 512 + (col & 7);
                for (int r = 0; r < 4; ++r)
                    Bs[ebase + (row + r) * 8] = f2bf(acc[mi][ni][r]);
            }
        __syncthreads();
        u16* dst = Ktl + ((size_t)(b * 32 + kt)) * 8192;
        for (int i = 0; i < 4; ++i)
            *reinterpret_cast<u16x8*>(&dst[(size_t)(i * 256 + tid) * 8]) =
                *reinterpret_cast<const u16x8*>(&Bs[(i * 256 + tid) * 8]);
    } else {
        for (int mi = 0; mi < 4; ++mi)
            for (int ni = 0; ni < 2; ++ni) {
                int row = mi * 16 + g * 4;                 // t_loc base
                int col = wc + ni * 16 + lr;               // d
                for (int r = 0; r < 4; ++r) {
                    int t_loc = row + r;
                    Bs[(t_loc >> 5) * 4096 + ((t_loc >> 3) & 3) * 1024 +
                       col * 8 + (t_loc & 7)] = f2bf(acc[mi][ni][r]);
                }
            }
        __syncthreads();
        u16* dst = Vtl + ((size_t)(b * 32 + kt)) * 8192;
        for (int i = 0; i < 4; ++i)
            *reinterpret_cast<u16x8*>(&dst[(size_t)(i * 256 + tid) * 8]) =
                *reinterpret_cast<const u16x8*>(&Bs[(i * 256 + tid) * 8]);
    }
}

// ---------------------------------------------------------------------------
// Kernel 2: causal flash attention, split-KV span 4, K+V staged in LDS.
// Grid (144, 8): per batch, qt' group gg=qt>>2 has gg+1 splits.
// 4 waves x 16 q-rows.  Swapped QK^T, per-lane scalar softmax.
// Partials (normalized O in bf16, m, l) for nsplit>1.
// ---------------------------------------------------------------------------
__global__ __launch_bounds__(256) void attn(
    const u16* __restrict__ Qw, const u16* __restrict__ Ktl,
    const u16* __restrict__ Vtl, float* __restrict__ out,
    u16* __restrict__ po, float* __restrict__ pm, float* __restrict__ pl)
{
    __shared__ alignas(16) u16 Ks[8192];     // [kk:4][cb:4][row:64][8]
    __shared__ alignas(16) u16 Vs[8192];     // [c:2][gk:4][d:128][8]
    constexpr int LDPW = 36;
    __shared__ u32 Plw[4][16 * LDPW];

    const int s = blockIdx.x;
    const int b = blockIdx.y;
    int gg = 0;
    while (s >= 2 * (gg + 1) * (gg + 2)) ++gg;       // group: qt in [4gg, 4gg+4)
    const int r_     = s - 2 * gg * (gg + 1);
    const int qt     = 4 * gg + r_ / (gg + 1);
    const int split  = r_ % (gg + 1);
    const int kt0 = split * 4;
    const int kt1 = min(kt0 + 4, qt + 1);

    const int tid  = threadIdx.x;
    const int wid  = tid >> 6;
    const int lane = tid & 63;
    const int g    = lane >> 4;
    const int lr   = lane & 15;
    const int qrow0 = qt * 64 + wid * 16;
    const int q = qrow0 + lr;

    const u16* Qp = Qw + ((size_t)(b * TDIM + qrow0)) * DDIM;
    bf16x8 qf[4];
    for (int kk = 0; kk < 4; ++kk)
        qf[kk] = __builtin_bit_cast(bf16x8, *reinterpret_cast<const u16x8*>(
            &Qp[lr * DDIM + kk * 32 + g * 8]));

    f32x4 o[8] = {};
    float mrow = -1e30f;
    float lsum = 0.f;
    u32* Pw = &Plw[wid][0];

    for (int kt = kt0; kt < kt1; ++kt) {
        const u16* Kt = Ktl + ((size_t)(b * 32 + kt)) * 8192;
        const u16* Vt = Vtl + ((size_t)(b * 32 + kt)) * 8192;
        for (int i = 0; i < 4; ++i)
            gload16(Kt + (size_t)(i * 256 + tid) * 8, &Ks[(i * 256 + wid * 64) * 8]);
        for (int i = 0; i < 4; ++i)
            gload16(Vt + (size_t)(i * 256 + tid) * 8, &Vs[(i * 256 + wid * 64) * 8]);
        __syncthreads();

        // S^T = K Q^T
        f32x4 sf[4] = {};
        for (int js = 0; js < 4; ++js)
            for (int kk = 0; kk < 4; ++kk) {
                bf16x8 kf = __builtin_bit_cast(bf16x8, *reinterpret_cast<const u16x8*>(
                    &Ks[kk * 2048 + g * 512 + (js * 16 + lr) * 8]));
                sf[js] = __builtin_amdgcn_mfma_f32_16x16x32_bf16(
                    kf, qf[kk], sf[js], 0, 0, 0);
            }

        // online softmax, per-lane scalar m/l (q-row = lr)
        float pv[4][4];
        float tmax = -1e30f;
        const bool maskt = (kt == qt);
        const int kvb = kt * 64 + g * 4;
        for (int js = 0; js < 4; ++js)
            for (int r = 0; r < 4; ++r) {
                float v = sf[js][r];
                if (maskt && (kvb + js * 16 + r) > q) v = -1e30f;
                pv[js][r] = v;
                tmax = fmaxf(tmax, v);
            }
        tmax = fmaxf(tmax, __shfl_xor(tmax, 16));
        tmax = fmaxf(tmax, __shfl_xor(tmax, 32));
        float nm = fmaxf(mrow, tmax);
        float al = __expf(mrow - nm);
        mrow = nm;
        float rs = 0.f;
        for (int js = 0; js < 4; ++js)
            for (int r = 0; r < 4; ++r) {
                float p = __expf(pv[js][r] - nm);
                pv[js][r] = p;
                rs += p;
            }
        rs += __shfl_xor(rs, 16);
        rs += __shfl_xor(rs, 32);
        lsum = lsum * al + rs;

        for (int js = 0; js < 4; ++js) {
            Pw[lr * LDPW + js * 8 + g * 2 + 0] = packbf(pv[js][0], pv[js][1]);
            Pw[lr * LDPW + js * 8 + g * 2 + 1] = packbf(pv[js][2], pv[js][3]);
        }

        float alo[4];
        for (int r = 0; r < 4; ++r)
            alo[r] = __shfl(al, g * 20 + r);
        for (int dt = 0; dt < 8; ++dt)
            for (int r = 0; r < 4; ++r)
                o[dt][r] *= alo[r];

        // PV
        for (int c = 0; c < 2; ++c) {
            u32x4 prd = *reinterpret_cast<const u32x4*>(&Pw[lr * LDPW + c * 16 + g * 4]);
            bf16x8 pf = __builtin_bit_cast(bf16x8, prd);
            for (int dt = 0; dt < 8; ++dt) {
                bf16x8 vf = __builtin_bit_cast(bf16x8, *reinterpret_cast<const u16x8*>(
                    &Vs[c * 4096 + g * 1024 + (dt * 16 + lr) * 8]));
                o[dt] = __builtin_amdgcn_mfma_f32_16x16x32_bf16(
                    pf, vf, o[dt], 0, 0, 0);
            }
        }
        __syncthreads();
    }

    float linv = 1.0f / lsum;
    float linvo[4];
    for (int r = 0; r < 4; ++r)
        linvo[r] = __shfl(linv, g * 20 + r);

    if (gg == 0) {
        float* orow = out + ((size_t)(b * TDIM + qrow0)) * DDIM;
        for (int dt = 0; dt < 8; ++dt)
            for (int r = 0; r < 4; ++r)
                orow[(size_t)(g * 4 + r) * DDIM + dt * 16 + lr] = o[dt][r] * linvo[r];
    } else {
        const int slot = (b * 32 + qt) * 8 + split;
        u16* pob = po + (size_t)slot * 8192 + (size_t)(wid * 16) * 128;
        for (int dt = 0; dt < 8; ++dt)
            for (int r = 0; r < 4; ++r)
                pob[(size_t)(g * 4 + r) * 128 + dt * 16 + lr] = f2bf(o[dt][r] * linvo[r]);
        if (g == 0) {
            pm[slot * 64 + wid * 16 + lr] = mrow;
            pl[slot * 64 + wid * 16 + lr] = lsum;
        }
    }
}

// ---------------------------------------------------------------------------
// Kernel 3: combine split-KV partials (qt >= 4).  out = sum_i w_i * O_i
// with w_i = l_i * exp(m_i - M) / L (weights sum to 1; O_i pre-normalized).
// ---------------------------------------------------------------------------
__global__ __launch_bounds__(256) void combine(
    const u16* __restrict__ po, const float* __restrict__ pm,
    const float* __restrict__ pl, float* __restrict__ out)
{
    const int qt = 4 + blockIdx.x;          // 4..31
    const int b  = blockIdx.y;
    const int nsplit = (qt >> 2) + 1;       // 2..8
    const int tid = threadIdx.x;
    const int row = tid >> 2;               // 0..63
    const int cs  = tid & 3;                // 32-col segment
    const int slot0 = (b * 32 + qt) * 8;

    float mv[8], wv[8];
    float M = -1e30f;
    #pragma unroll 8
    for (int i = 0; i < 8; ++i)
        if (i < nsplit) { mv[i] = pm[(slot0 + i) * 64 + row]; M = fmaxf(M, mv[i]); }
    float L = 0.f;
    #pragma unroll 8
    for (int i = 0; i < 8; ++i)
        if (i < nsplit) { wv[i] = pl[(slot0 + i) * 64 + row] * __expf(mv[i] - M); L += wv[i]; }
    float invL = 1.0f / L;

    float acc[32] = {};
    #pragma unroll 8
    for (int i = 0; i < 8; ++i)
        if (i < nsplit) {
            float w = wv[i] * invL;
            const u16* pr = &po[(size_t)(slot0 + i) * 8192 + (size_t)row * 128 + cs * 32];
            for (int j2 = 0; j2 < 4; ++j2) {
                u16x8 v = *reinterpret_cast<const u16x8*>(&pr[j2 * 8]);
                for (int e = 0; e < 8; ++e)
                    acc[j2 * 8 + e] += w * bf2f(v[e]);
            }
        }
    float* orow = &out[((size_t)(b * TDIM) + qt * 64 + row) * DDIM + cs * 32];
    for (int j4 = 0; j4 < 8; ++j4) {
        f32x4 v;
        v[0] = acc[j4*4+0]; v[1] = acc[j4*4+1]; v[2] = acc[j4*4+2]; v[3] = acc[j4*4+3];
        *reinterpret_cast<f32x4*>(&orow[j4 * 4]) = v;
    }
}

extern "C" void kernel_launch(void* const* d_in, const int* in_sizes, int n_in,
                              void* d_out, int out_size, void* d_ws, size_t ws_size,
                              hipStream_t stream) {
    const float* x  = (const float*)d_in[0];
    const float* Wq = (const float*)d_in[1];
    const float* Wk = (const float*)d_in[2];
    const float* Wv = (const float*)d_in[3];
    float* out = (float*)d_out;

    char* base = (char*)d_ws;
    u16*   wb  = (u16*)base;                          // 0.75 MB tiled W
    u16*   Qw  = (u16*)(base + 0x100000);             // 4 MB  [t][128]
    u16*   Ktl = (u16*)(base + 0x500000);             // 4 MB  tiles
    u16*   Vtl = (u16*)(base + 0x900000);             // 4 MB  tiles
    u16*   po  = (u16*)(base + 0xD00000);             // 32 MB bf16 partials
    float* pm  = (float*)(base + 0x2D00000);          // 512 KB
    float* pl  = (float*)(base + 0x2D80000);          // 512 KB

    convert_w<<<dim3(48), dim3(256), 0, stream>>>(Wq, Wk, Wv, wb);
    qkv_gemm<<<dim3(768), dim3(256), 0, stream>>>(x, wb, Qw, Ktl, Vtl);
    attn<<<dim3(144, BATCH), dim3(256), 0, stream>>>(Qw, Ktl, Vtl, out, po, pm, pl);
    combine<<<dim3(28, BATCH), dim3(256), 0, stream>>>(po, pm, pl, out);
}